// Round 1
// baseline (1869.605 us; speedup 1.0000x reference)
//
#include <hip/hip_runtime.h>
#include <cmath>

#define HD 512      // hidden
#define IN 512      // input features
#define TT 784      // timesteps
#define BB 128      // batch

// ---------------- GEMM: d[m,n] = sum_k X[row(m),k] * W[n,k] + bias[n] -------
// M = 128*Tc (chunk rows), N = 1024 (W1 cols 0..511 -> d1buf, W2 -> d2buf), K = 512
#define BM 128
#define BN 128
#define BK 16

__global__ __launch_bounds__(256) void branch_gemm(
    const float* __restrict__ X,
    const float* __restrict__ W1, const float* __restrict__ W2,
    const float* __restrict__ b1, const float* __restrict__ b2,
    float* __restrict__ d1buf, float* __restrict__ d2buf,
    int t0, int Tc)
{
    __shared__ float As[BK][BM + 4];
    __shared__ float Bs[BK][BN + 4];
    const int tid = threadIdx.x;
    const int pn = blockIdx.x & 7;          // 8 col-blocks over N=1024
    const int pm = blockIdx.x >> 3;
    const int m0 = pm * BM;
    const int n0 = pn * BN;
    const bool first = (n0 < HD);
    const float* __restrict__ W    = first ? W1 : W2;
    const float* __restrict__ bias = first ? b1 : b2;
    float* __restrict__ obuf       = first ? d1buf : d2buf;
    const int nc0 = n0 & (HD - 1);

    const int lrow = tid >> 2;              // 0..63
    const int lcol = (tid & 3) << 2;        // 0,4,8,12

    const float* aptr[2];
    const float* wptr[2];
#pragma unroll
    for (int r = 0; r < 2; ++r) {
        int m  = m0 + lrow + r * 64;
        int b  = m / Tc;
        int tc = m - b * Tc;
        aptr[r] = X + (size_t)(b * TT + t0 + tc) * IN + lcol;
        wptr[r] = W + (size_t)(nc0 + lrow + r * 64) * IN + lcol;
    }

    float acc[8][8];
#pragma unroll
    for (int i = 0; i < 8; ++i)
#pragma unroll
        for (int j = 0; j < 8; ++j) acc[i][j] = 0.f;

    const int ty = tid >> 4;   // 0..15
    const int tx = tid & 15;   // 0..15

    for (int k0 = 0; k0 < IN; k0 += BK) {
        float4 av[2], bv[2];
#pragma unroll
        for (int r = 0; r < 2; ++r) {
            av[r] = *(const float4*)(aptr[r] + k0);
            bv[r] = *(const float4*)(wptr[r] + k0);
        }
        __syncthreads();
#pragma unroll
        for (int r = 0; r < 2; ++r) {
            As[lcol + 0][lrow + r * 64] = av[r].x;
            As[lcol + 1][lrow + r * 64] = av[r].y;
            As[lcol + 2][lrow + r * 64] = av[r].z;
            As[lcol + 3][lrow + r * 64] = av[r].w;
            Bs[lcol + 0][lrow + r * 64] = bv[r].x;
            Bs[lcol + 1][lrow + r * 64] = bv[r].y;
            Bs[lcol + 2][lrow + r * 64] = bv[r].z;
            Bs[lcol + 3][lrow + r * 64] = bv[r].w;
        }
        __syncthreads();
#pragma unroll
        for (int k = 0; k < BK; ++k) {
            float af[8], bf[8];
            *(float4*)&af[0] = *(const float4*)&As[k][ty * 8];
            *(float4*)&af[4] = *(const float4*)&As[k][ty * 8 + 4];
            *(float4*)&bf[0] = *(const float4*)&Bs[k][tx * 8];
            *(float4*)&bf[4] = *(const float4*)&Bs[k][tx * 8 + 4];
#pragma unroll
            for (int i = 0; i < 8; ++i)
#pragma unroll
                for (int j = 0; j < 8; ++j)
                    acc[i][j] = fmaf(af[i], bf[j], acc[i][j]);
        }
    }

    // epilogue: add bias, store
#pragma unroll
    for (int i = 0; i < 8; ++i) {
        int m = m0 + ty * 8 + i;
        float* op = obuf + (size_t)m * HD + nc0 + tx * 8;
        float4 o0, o1;
        o0.x = acc[i][0] + bias[nc0 + tx * 8 + 0];
        o0.y = acc[i][1] + bias[nc0 + tx * 8 + 1];
        o0.z = acc[i][2] + bias[nc0 + tx * 8 + 2];
        o0.w = acc[i][3] + bias[nc0 + tx * 8 + 3];
        o1.x = acc[i][4] + bias[nc0 + tx * 8 + 4];
        o1.y = acc[i][5] + bias[nc0 + tx * 8 + 5];
        o1.z = acc[i][6] + bias[nc0 + tx * 8 + 6];
        o1.w = acc[i][7] + bias[nc0 + tx * 8 + 7];
        *(float4*)(op)     = o0;
        *(float4*)(op + 4) = o1;
    }
}

// ---------------- Scan: per-(b,h) neuron recurrence over a chunk of T -------
__global__ __launch_bounds__(256) void scan_step(
    const float* __restrict__ d1buf, const float* __restrict__ d2buf,
    const float* __restrict__ tau_m, const float* __restrict__ tau_n1,
    const float* __restrict__ tau_n2,
    const float* __restrict__ mem0, const float* __restrict__ spike0,
    float* __restrict__ mem_s, float* __restrict__ spk_s,
    float* __restrict__ d1_s, float* __restrict__ d2_s,
    unsigned short* __restrict__ spikes,
    int chunk, int Tc)
{
    const int gid = blockIdx.x * blockDim.x + threadIdx.x;   // 0..65535
    const int h = gid & (HD - 1);
    const int b = gid >> 9;
    const float alpha = 1.f / (1.f + expf(-tau_m[h]));
    const float be1   = 1.f / (1.f + expf(-tau_n1[h]));
    const float be2   = 1.f / (1.f + expf(-tau_n2[h]));
    float mem, spk, d1, d2;
    if (chunk == 0) {
        mem = mem0[gid]; spk = spike0[gid]; d1 = 0.f; d2 = 0.f;
    } else {
        mem = mem_s[gid]; spk = spk_s[gid]; d1 = d1_s[gid]; d2 = d2_s[gid];
    }
    const float* p1 = d1buf + (size_t)b * Tc * HD + h;
    const float* p2 = d2buf + (size_t)b * Tc * HD + h;
    unsigned short* sp = spikes + ((size_t)b * (TT / 16) + (size_t)chunk * (Tc / 16)) * HD + h;

    unsigned int word = 0;
    for (int tc = 0; tc < Tc; ++tc) {
        float d1t = p1[(size_t)tc * HD];
        float d2t = p2[(size_t)tc * HD];
        d1 = be1 * d1 + (1.f - be1) * d1t;
        d2 = be2 * d2 + (1.f - be2) * d2t;
        float total = d1 + d2;
        mem = mem * alpha + (1.f - alpha) * total - spk;
        bool fire = (mem - 1.0f) > 0.f;
        spk = fire ? 1.f : 0.f;
        word |= (fire ? 1u : 0u) << (tc & 15);
        if ((tc & 15) == 15) {
            sp[(size_t)(tc >> 4) * HD] = (unsigned short)word;
            word = 0;
        }
    }
    mem_s[gid] = mem; spk_s[gid] = spk; d1_s[gid] = d1; d2_s[gid] = d2;
}

// ---------------- Readout: out[b,t,o] = br[o] + sum_h spk(b,t,h)*Wr[o,h] ----
__global__ __launch_bounds__(256) void readout(
    const unsigned short* __restrict__ spikes,
    const float* __restrict__ Wr, const float* __restrict__ br,
    float* __restrict__ out)
{
    __shared__ float WrS[10 * HD];   // 20 KB, layout [o][h]
    __shared__ float brS[10];
    const int tid = threadIdx.x;
    for (int i = tid; i < 10 * HD; i += 256) WrS[i] = Wr[i];
    if (tid < 10) brS[tid] = br[tid];
    __syncthreads();

    const int gid = blockIdx.x * 256 + tid;      // 0..100351 = b*784+t
    const int t = gid % TT;
    const int b = gid / TT;
    const int tw  = t >> 4;
    const int bit = t & 15;
    const unsigned short* row = spikes + ((size_t)b * (TT / 16) + tw) * HD;

    float acc[10];
#pragma unroll
    for (int o = 0; o < 10; ++o) acc[o] = brS[o];

    for (int h = 0; h < HD; ++h) {
        float s = (float)((row[h] >> bit) & 1);
#pragma unroll
        for (int o = 0; o < 10; ++o) acc[o] = fmaf(s, WrS[o * HD + h], acc[o]);
    }
    float* op = out + (size_t)gid * 10;
#pragma unroll
    for (int o = 0; o < 10; ++o) op[o] = acc[o];
}

// ---------------------------------------------------------------------------
extern "C" void kernel_launch(void* const* d_in, const int* in_sizes, int n_in,
                              void* d_out, int out_size, void* d_ws, size_t ws_size,
                              hipStream_t stream)
{
    const float* X      = (const float*)d_in[0];
    const float* W1     = (const float*)d_in[1];
    const float* b1     = (const float*)d_in[2];
    const float* W2     = (const float*)d_in[3];
    const float* b2     = (const float*)d_in[4];
    const float* tau_m  = (const float*)d_in[5];
    const float* tau_n1 = (const float*)d_in[6];
    const float* tau_n2 = (const float*)d_in[7];
    const float* Wr     = (const float*)d_in[8];
    const float* br     = (const float*)d_in[9];
    const float* mem0   = (const float*)d_in[10];
    const float* spike0 = (const float*)d_in[11];
    float* out = (float*)d_out;

    const size_t state_bytes = 4 * (size_t)BB * HD * sizeof(float);          // 1 MB
    const size_t spike_bytes = (size_t)BB * (TT / 16) * HD * sizeof(unsigned short); // 6.4 MB
    auto need = [&](int tc) {
        return 2 * (size_t)BB * tc * HD * sizeof(float) + state_bytes + spike_bytes;
    };
    // Tc must be a multiple of 16 dividing 784: {16, 112, 784}
    int Tc = 16;
    if (ws_size >= need(784)) Tc = 784;
    else if (ws_size >= need(112)) Tc = 112;
    const int nch = TT / Tc;

    const size_t dbytes = (size_t)BB * Tc * HD * sizeof(float);
    float* d1buf = (float*)d_ws;
    float* d2buf = (float*)((char*)d_ws + dbytes);
    float* mem_s = (float*)((char*)d_ws + 2 * dbytes);
    float* spk_s = mem_s + BB * HD;
    float* d1_s  = spk_s + BB * HD;
    float* d2_s  = d1_s + BB * HD;
    unsigned short* spikes = (unsigned short*)(d2_s + BB * HD);

    for (int c = 0; c < nch; ++c) {
        branch_gemm<<<dim3(Tc * 8), dim3(256), 0, stream>>>(
            X, W1, W2, b1, b2, d1buf, d2buf, c * Tc, Tc);
        scan_step<<<dim3((BB * HD) / 256), dim3(256), 0, stream>>>(
            d1buf, d2buf, tau_m, tau_n1, tau_n2, mem0, spike0,
            mem_s, spk_s, d1_s, d2_s, spikes, c, Tc);
    }
    readout<<<dim3((BB * TT) / 256), dim3(256), 0, stream>>>(spikes, Wr, br, out);
}

// Round 4
// 1716.510 us; speedup vs baseline: 1.0892x; 1.0892x over previous
//
#include <hip/hip_runtime.h>
#include <cmath>

#define HD 512      // hidden
#define IN 512      // input features (K)
#define TT 784      // timesteps
#define BB 128      // batch
#define TC 112      // chunk timesteps (112*7 = 784)
#define NCH (TT / TC)
#define MC (BB * TC)   // 14336 rows per chunk

// ---------------- GEMM: d[m,n] = sum_k X[row(m),k] * W[n,k] + bias[n] -------
// fp32 vector-ALU (validated numerics, round 1). M = 14336, N = 1024, K = 512.
// Changes vs round 1: bank-swizzled LDS (kills the 4-way read conflicts that
// cost 1.285e8 conflict-cycles), register prefetch of next K-slab.
#define BM 128
#define BN 128
#define BK 16
#define LDC 164    // padded/swizzled row stride in floats

__device__ __forceinline__ int swz(int col, int k) {
    // skew within a row to break the stride-8-float 4-way pattern (2-way max),
    // plus a k-dependent rotation so writer row-groups land on distinct banks.
    return col + ((col >> 5) << 2) + (((k >> 2) & 3) << 3);
}

__global__ __launch_bounds__(256) void branch_gemm(
    const float* __restrict__ X,
    const float* __restrict__ W1, const float* __restrict__ W2,
    const float* __restrict__ b1, const float* __restrict__ b2,
    float* __restrict__ d1buf, float* __restrict__ d2buf,
    int t0)
{
    __shared__ float As[BK * LDC];
    __shared__ float Bs[BK * LDC];
    const int tid = threadIdx.x;
    const int pn = blockIdx.x & 7;          // 8 col-blocks over N=1024
    const int pm = blockIdx.x >> 3;         // 112 row-blocks over M=14336
    const int m0 = pm * BM;
    const int n0 = pn * BN;
    const bool first = (n0 < HD);
    const float* __restrict__ W    = first ? W1 : W2;
    const float* __restrict__ bias = first ? b1 : b2;
    float* __restrict__ obuf       = first ? d1buf : d2buf;
    const int nc0 = n0 & (HD - 1);

    const int lrow = tid >> 2;              // 0..63
    const int lcol = (tid & 3) << 2;        // 0,4,8,12

    const float* aptr[2];
    const float* wptr[2];
#pragma unroll
    for (int r = 0; r < 2; ++r) {
        int m  = m0 + lrow + r * 64;
        int b  = m / TC;
        int tc = m - b * TC;
        aptr[r] = X + (size_t)(b * TT + t0 + tc) * IN + lcol;
        wptr[r] = W + (size_t)(nc0 + lrow + r * 64) * IN + lcol;
    }

    float acc[8][8];
#pragma unroll
    for (int i = 0; i < 8; ++i)
#pragma unroll
        for (int j = 0; j < 8; ++j) acc[i][j] = 0.f;

    const int ty = tid >> 4;   // 0..15 -> m sub-block
    const int tx = tid & 15;   // 0..15 -> n sub-block

    // prefetch first K-slab into registers
    float4 av[2], bv[2];
#pragma unroll
    for (int r = 0; r < 2; ++r) {
        av[r] = *(const float4*)(aptr[r]);
        bv[r] = *(const float4*)(wptr[r]);
    }

    for (int k0 = 0; k0 < IN; k0 += BK) {
        __syncthreads();
#pragma unroll
        for (int r = 0; r < 2; ++r) {
            const int colA = lrow + r * 64;
            const float* avf = (const float*)&av[r];
            const float* bvf = (const float*)&bv[r];
#pragma unroll
            for (int j = 0; j < 4; ++j) {
                As[(lcol + j) * LDC + swz(colA, lcol + j)] = avf[j];
                Bs[(lcol + j) * LDC + swz(colA, lcol + j)] = bvf[j];
            }
        }
        __syncthreads();
        if (k0 + BK < IN) {   // issue next slab's global loads; overlap compute
#pragma unroll
            for (int r = 0; r < 2; ++r) {
                av[r] = *(const float4*)(aptr[r] + k0 + BK);
                bv[r] = *(const float4*)(wptr[r] + k0 + BK);
            }
        }
#pragma unroll
        for (int k = 0; k < BK; ++k) {
            float af[8], bf[8];
            const int sa = k * LDC + swz(ty * 8, k);
            const int sb = k * LDC + swz(tx * 8, k);
            *(float4*)&af[0] = *(const float4*)&As[sa];
            *(float4*)&af[4] = *(const float4*)&As[sa + 4];
            *(float4*)&bf[0] = *(const float4*)&Bs[sb];
            *(float4*)&bf[4] = *(const float4*)&Bs[sb + 4];
#pragma unroll
            for (int i = 0; i < 8; ++i)
#pragma unroll
                for (int j = 0; j < 8; ++j)
                    acc[i][j] = fmaf(af[i], bf[j], acc[i][j]);
        }
    }

    // epilogue: add bias, store (identical to validated round-1 epilogue)
#pragma unroll
    for (int i = 0; i < 8; ++i) {
        int m = m0 + ty * 8 + i;
        float* op = obuf + (size_t)m * HD + nc0 + tx * 8;
        float4 o0, o1;
        o0.x = acc[i][0] + bias[nc0 + tx * 8 + 0];
        o0.y = acc[i][1] + bias[nc0 + tx * 8 + 1];
        o0.z = acc[i][2] + bias[nc0 + tx * 8 + 2];
        o0.w = acc[i][3] + bias[nc0 + tx * 8 + 3];
        o1.x = acc[i][4] + bias[nc0 + tx * 8 + 4];
        o1.y = acc[i][5] + bias[nc0 + tx * 8 + 5];
        o1.z = acc[i][6] + bias[nc0 + tx * 8 + 6];
        o1.w = acc[i][7] + bias[nc0 + tx * 8 + 7];
        *(float4*)(op)     = o0;
        *(float4*)(op + 4) = o1;
    }
}

// ---------------- Scan: per-(b,h) neuron recurrence over one chunk ----------
__global__ __launch_bounds__(256) void scan_step(
    const float* __restrict__ d1buf, const float* __restrict__ d2buf,
    const float* __restrict__ tau_m, const float* __restrict__ tau_n1,
    const float* __restrict__ tau_n2,
    const float* __restrict__ mem0, const float* __restrict__ spike0,
    float* __restrict__ mem_s, float* __restrict__ spk_s,
    float* __restrict__ d1_s, float* __restrict__ d2_s,
    unsigned short* __restrict__ spikes, int chunk)
{
    const int gid = blockIdx.x * blockDim.x + threadIdx.x;   // 0..65535
    const int h = gid & (HD - 1);
    const int b = gid >> 9;
    const float alpha = 1.f / (1.f + expf(-tau_m[h]));
    const float be1   = 1.f / (1.f + expf(-tau_n1[h]));
    const float be2   = 1.f / (1.f + expf(-tau_n2[h]));
    float mem, spk, d1, d2;
    if (chunk == 0) {
        mem = mem0[gid]; spk = spike0[gid]; d1 = 0.f; d2 = 0.f;
    } else {
        mem = mem_s[gid]; spk = spk_s[gid]; d1 = d1_s[gid]; d2 = d2_s[gid];
    }
    const float* p1 = d1buf + (size_t)b * TC * HD + h;
    const float* p2 = d2buf + (size_t)b * TC * HD + h;
    unsigned short* sp = spikes + ((size_t)b * (TT / 16) + chunk * (TC / 16)) * HD + h;

#pragma unroll 1
    for (int g = 0; g < TC / 16; ++g) {
        float a1[16], a2[16];
#pragma unroll
        for (int i = 0; i < 16; ++i) {
            a1[i] = p1[(size_t)(g * 16 + i) * HD];
            a2[i] = p2[(size_t)(g * 16 + i) * HD];
        }
        unsigned int word = 0;
#pragma unroll
        for (int i = 0; i < 16; ++i) {
            d1 = be1 * d1 + (1.f - be1) * a1[i];
            d2 = be2 * d2 + (1.f - be2) * a2[i];
            float total = d1 + d2;
            mem = mem * alpha + (1.f - alpha) * total - spk;
            bool fire = (mem - 1.0f) > 0.f;
            spk = fire ? 1.f : 0.f;
            word |= (fire ? 1u : 0u) << i;
        }
        sp[(size_t)g * HD] = (unsigned short)word;
    }
    mem_s[gid] = mem; spk_s[gid] = spk; d1_s[gid] = d1; d2_s[gid] = d2;
}

// ---------------- Readout (round-1 validated version) -----------------------
__global__ __launch_bounds__(256) void readout(
    const unsigned short* __restrict__ spikes,
    const float* __restrict__ Wr, const float* __restrict__ br,
    float* __restrict__ out)
{
    __shared__ float WrS[10 * HD];   // 20 KB, layout [o][h]
    __shared__ float brS[10];
    const int tid = threadIdx.x;
    for (int i = tid; i < 10 * HD; i += 256) WrS[i] = Wr[i];
    if (tid < 10) brS[tid] = br[tid];
    __syncthreads();

    const int gid = blockIdx.x * 256 + tid;      // 0..100351 = b*784+t
    const int t = gid % TT;
    const int b = gid / TT;
    const int tw  = t >> 4;
    const int bit = t & 15;
    const unsigned short* row = spikes + ((size_t)b * (TT / 16) + tw) * HD;

    float acc[10];
#pragma unroll
    for (int o = 0; o < 10; ++o) acc[o] = brS[o];

    for (int h = 0; h < HD; ++h) {
        float s = (float)((row[h] >> bit) & 1);
#pragma unroll
        for (int o = 0; o < 10; ++o) acc[o] = fmaf(s, WrS[o * HD + h], acc[o]);
    }
    float* op = out + (size_t)gid * 10;
#pragma unroll
    for (int o = 0; o < 10; ++o) op[o] = acc[o];
}

// ---------------------------------------------------------------------------
extern "C" void kernel_launch(void* const* d_in, const int* in_sizes, int n_in,
                              void* d_out, int out_size, void* d_ws, size_t ws_size,
                              hipStream_t stream)
{
    const float* X      = (const float*)d_in[0];
    const float* W1     = (const float*)d_in[1];
    const float* b1     = (const float*)d_in[2];
    const float* W2     = (const float*)d_in[3];
    const float* b2     = (const float*)d_in[4];
    const float* tau_m  = (const float*)d_in[5];
    const float* tau_n1 = (const float*)d_in[6];
    const float* tau_n2 = (const float*)d_in[7];
    const float* Wr     = (const float*)d_in[8];
    const float* br     = (const float*)d_in[9];
    const float* mem0   = (const float*)d_in[10];
    const float* spike0 = (const float*)d_in[11];
    float* out = (float*)d_out;

    char* p = (char*)d_ws;
    float* d1buf = (float*)p;     p += (size_t)MC * HD * sizeof(float);
    float* d2buf = (float*)p;     p += (size_t)MC * HD * sizeof(float);
    float* mem_s = (float*)p;     p += (size_t)BB * HD * sizeof(float);
    float* spk_s = (float*)p;     p += (size_t)BB * HD * sizeof(float);
    float* d1_s  = (float*)p;     p += (size_t)BB * HD * sizeof(float);
    float* d2_s  = (float*)p;     p += (size_t)BB * HD * sizeof(float);
    unsigned short* spikes = (unsigned short*)p;

    for (int c = 0; c < NCH; ++c) {
        branch_gemm<<<dim3(112 * 8), dim3(256), 0, stream>>>(
            X, W1, W2, b1, b2, d1buf, d2buf, c * TC);
        scan_step<<<dim3((BB * HD) / 256), dim3(256), 0, stream>>>(
            d1buf, d2buf, tau_m, tau_n1, tau_n2, mem0, spike0,
            mem_s, spk_s, d1_s, d2_s, spikes, c);
    }
    readout<<<dim3((BB * TT) / 256), dim3(256), 0, stream>>>(spikes, Wr, br, out);
}

// Round 5
// 1115.971 us; speedup vs baseline: 1.6753x; 1.5381x over previous
//
#include <hip/hip_runtime.h>
#include <cmath>

#define HD 512      // hidden
#define IN 512      // input features (K)
#define TT 784      // timesteps
#define BB 128      // batch
#define MH 50176    // rows per batch-half (64 * 784)

typedef short short8 __attribute__((ext_vector_type(8)));
typedef unsigned short ushort8 __attribute__((ext_vector_type(8)));
typedef float floatx4 __attribute__((ext_vector_type(4)));

#define GLDS(gp, lp) __builtin_amdgcn_global_load_lds( \
    (const __attribute__((address_space(1))) void*)(gp), \
    (__attribute__((address_space(3))) void*)(lp), 16, 0, 0)

__device__ __forceinline__ unsigned short bf16_rne(float x) {
    unsigned u = __float_as_uint(x);
    unsigned r = u + 0x7FFFu + ((u >> 16) & 1u);
    return (unsigned short)(r >> 16);
}
__device__ __forceinline__ float bf16_f(unsigned short s) {
    return __uint_as_float(((unsigned)s) << 16);
}

// ---------------- split fp32 -> 3 bf16 planes (exact residual chain) --------
__global__ __launch_bounds__(256) void split3(
    const float* __restrict__ src, unsigned short* __restrict__ p1,
    unsigned short* __restrict__ p2, unsigned short* __restrict__ p3, long n8)
{
    long g = (long)blockIdx.x * 256 + threadIdx.x;
    if (g >= n8) return;
    const float* xp = src + g * 8;
    ushort8 o1, o2, o3;
#pragma unroll
    for (int j = 0; j < 8; ++j) {
        float x = xp[j];
        unsigned short s1 = bf16_rne(x);
        float r1 = x - bf16_f(s1);                 // exact in fp32
        unsigned short s2 = bf16_rne(r1);
        float r2 = r1 - bf16_f(s2);                // exact in fp32
        unsigned short s3 = bf16_rne(r2);
        o1[j] = s1; o2[j] = s2; o3[j] = s3;
    }
    *(ushort8*)(p1 + g * 8) = o1;
    *(ushort8*)(p2 + g * 8) = o2;
    *(ushort8*)(p3 + g * 8) = o3;
}

// ---------------- MFMA GEMM (bf16x3): d = X*W^T + bias ----------------------
// X*W ~= a1b1 + (a1b2 + a2b1) + (a1b3 + a2b2 + a3b1), fp32 accum.
// 128x128 tile, 4 waves of 64x64, 16x16x32 MFMA, K-step 32. 48 KB LDS.
__global__ __launch_bounds__(256, 2) void gemm_bf16x3(
    const unsigned short* __restrict__ Xp,   // [3][MH][512]
    const unsigned short* __restrict__ Wp,   // [3][1024][512]
    const float* __restrict__ b1, const float* __restrict__ b2,
    float* __restrict__ d1buf, float* __restrict__ d2buf)
{
    __shared__ unsigned short lds[6][128][32];   // A1,A2,A3,B1,B2,B3
    unsigned short* lflat = &lds[0][0][0];
    const int tid  = threadIdx.x;
    const int lane = tid & 63;
    const int w    = tid >> 6;
    const int pn = blockIdx.x & 7;      // 8 n-blocks over N=1024
    const int pm = blockIdx.x >> 3;     // 392 m-blocks over MH
    const int m0 = pm * 128;
    const int n0 = pn * 128;

    // 12 staging pointers per wave: seg = w*12 + j covers 48 segments of
    // 16 rows x 32 cols (1 KB); GLDS writes base + lane*16B.
    const unsigned short* gp[12];
    {
        const int rsub = lane >> 2;          // row within 16-row segment
        const int csub = (lane & 3) * 8;     // ushort offset within row
#pragma unroll
        for (int j = 0; j < 12; ++j) {
            int seg = w * 12 + j;
            int p = seg >> 3, sub = seg & 7;
            int row16 = sub * 16 + rsub;
            gp[j] = (p < 3)
              ? Xp + ((size_t)p * MH + m0 + row16) * IN + csub
              : Wp + ((size_t)(p - 3) * 1024 + n0 + row16) * IN + csub;
        }
    }

    floatx4 acc[4][4];
#pragma unroll
    for (int i = 0; i < 4; ++i)
#pragma unroll
        for (int j = 0; j < 4; ++j) acc[i][j] = (floatx4){0.f, 0.f, 0.f, 0.f};

    const int wm = w >> 1, wn = w & 1;
    const int c16 = lane & 15;
    const int q8  = (lane >> 4) * 8;

    for (int ks = 0; ks < IN; ks += 32) {
#pragma unroll
        for (int j = 0; j < 12; ++j)
            GLDS(gp[j] + ks, lflat + (size_t)(w * 12 + j) * 512);
        __syncthreads();

        short8 Bf[3][4];
#pragma unroll
        for (int p = 0; p < 3; ++p)
#pragma unroll
            for (int fj = 0; fj < 4; ++fj)
                Bf[p][fj] = *(const short8*)&lds[3 + p][wn * 64 + fj * 16 + c16][q8];

#pragma unroll
        for (int fi = 0; fi < 4; ++fi) {
            const int r = wm * 64 + fi * 16 + c16;
            short8 a1 = *(const short8*)&lds[0][r][q8];
            short8 a2 = *(const short8*)&lds[1][r][q8];
            short8 a3 = *(const short8*)&lds[2][r][q8];
#pragma unroll
            for (int fj = 0; fj < 4; ++fj) {
                floatx4 c = acc[fi][fj];
                c = __builtin_amdgcn_mfma_f32_16x16x32_bf16(a3, Bf[0][fj], c, 0, 0, 0);
                c = __builtin_amdgcn_mfma_f32_16x16x32_bf16(a2, Bf[1][fj], c, 0, 0, 0);
                c = __builtin_amdgcn_mfma_f32_16x16x32_bf16(a1, Bf[2][fj], c, 0, 0, 0);
                c = __builtin_amdgcn_mfma_f32_16x16x32_bf16(a2, Bf[0][fj], c, 0, 0, 0);
                c = __builtin_amdgcn_mfma_f32_16x16x32_bf16(a1, Bf[1][fj], c, 0, 0, 0);
                c = __builtin_amdgcn_mfma_f32_16x16x32_bf16(a1, Bf[0][fj], c, 0, 0, 0);
                acc[fi][fj] = c;
            }
        }
        __syncthreads();
    }

    // epilogue: C layout col=lane&15, row=(lane>>4)*4+reg (m89-verified)
    const int quad = lane >> 4;
    const bool first = (n0 < HD);
    const float* bias = first ? b1 : b2;
    float* obuf = first ? d1buf : d2buf;
    const int nb = n0 & (HD - 1);
    float bv[4];
#pragma unroll
    for (int fj = 0; fj < 4; ++fj) bv[fj] = bias[nb + wn * 64 + fj * 16 + c16];
#pragma unroll
    for (int fi = 0; fi < 4; ++fi) {
#pragma unroll
        for (int fj = 0; fj < 4; ++fj) {
            int n = nb + wn * 64 + fj * 16 + c16;
#pragma unroll
            for (int r = 0; r < 4; ++r) {
                int m = m0 + wm * 64 + fi * 16 + quad * 4 + r;
                obuf[(size_t)m * HD + n] = acc[fi][fj][r] + bv[fj];
            }
        }
    }
}

// ---------------- Scan: full T per (b,h), one batch-half per dispatch -------
__global__ __launch_bounds__(64) void scan_half(
    const float* __restrict__ d1buf, const float* __restrict__ d2buf,
    const float* __restrict__ tau_m, const float* __restrict__ tau_n1,
    const float* __restrict__ tau_n2,
    const float* __restrict__ mem0, const float* __restrict__ spike0,
    unsigned short* __restrict__ spikes, int b0)
{
    const int gid = blockIdx.x * 64 + threadIdx.x;   // 0..32767
    const int h  = gid & (HD - 1);
    const int bl = gid >> 9;                          // local batch 0..63
    const int b  = b0 + bl;
    const float alpha = 1.f / (1.f + expf(-tau_m[h]));
    const float be1   = 1.f / (1.f + expf(-tau_n1[h]));
    const float be2   = 1.f / (1.f + expf(-tau_n2[h]));
    float mem = mem0[b * HD + h];
    float spk = spike0[b * HD + h];
    float d1 = 0.f, d2 = 0.f;
    const float* p1 = d1buf + (size_t)bl * TT * HD + h;
    const float* p2 = d2buf + (size_t)bl * TT * HD + h;
    unsigned short* sp = spikes + (size_t)b * (TT / 16) * HD + h;

#pragma unroll 1
    for (int g = 0; g < TT / 16; ++g) {
        float a1[16], a2[16];
#pragma unroll
        for (int i = 0; i < 16; ++i) {
            a1[i] = p1[(size_t)(g * 16 + i) * HD];
            a2[i] = p2[(size_t)(g * 16 + i) * HD];
        }
        unsigned int word = 0;
#pragma unroll
        for (int i = 0; i < 16; ++i) {
            d1 = be1 * d1 + (1.f - be1) * a1[i];
            d2 = be2 * d2 + (1.f - be2) * a2[i];
            float total = d1 + d2;
            mem = mem * alpha + (1.f - alpha) * total - spk;
            bool fire = (mem - 1.0f) > 0.f;
            spk = fire ? 1.f : 0.f;
            word |= (fire ? 1u : 0u) << i;
        }
        sp[(size_t)g * HD] = (unsigned short)word;
    }
}

// ---------------- Readout (round-1/4 validated) -----------------------------
__global__ __launch_bounds__(256) void readout(
    const unsigned short* __restrict__ spikes,
    const float* __restrict__ Wr, const float* __restrict__ br,
    float* __restrict__ out)
{
    __shared__ float WrS[10 * HD];   // 20 KB, layout [o][h]
    __shared__ float brS[10];
    const int tid = threadIdx.x;
    for (int i = tid; i < 10 * HD; i += 256) WrS[i] = Wr[i];
    if (tid < 10) brS[tid] = br[tid];
    __syncthreads();

    const int gid = blockIdx.x * 256 + tid;      // 0..100351 = b*784+t
    const int t = gid % TT;
    const int b = gid / TT;
    const int tw  = t >> 4;
    const int bit = t & 15;
    const unsigned short* row = spikes + ((size_t)b * (TT / 16) + tw) * HD;

    float acc[10];
#pragma unroll
    for (int o = 0; o < 10; ++o) acc[o] = brS[o];

    for (int h = 0; h < HD; ++h) {
        float s = (float)((row[h] >> bit) & 1);
#pragma unroll
        for (int o = 0; o < 10; ++o) acc[o] = fmaf(s, WrS[o * HD + h], acc[o]);
    }
    float* op = out + (size_t)gid * 10;
#pragma unroll
    for (int o = 0; o < 10; ++o) op[o] = acc[o];
}

// ---------------------------------------------------------------------------
extern "C" void kernel_launch(void* const* d_in, const int* in_sizes, int n_in,
                              void* d_out, int out_size, void* d_ws, size_t ws_size,
                              hipStream_t stream)
{
    const float* X      = (const float*)d_in[0];
    const float* W1     = (const float*)d_in[1];
    const float* b1     = (const float*)d_in[2];
    const float* W2     = (const float*)d_in[3];
    const float* b2     = (const float*)d_in[4];
    const float* tau_m  = (const float*)d_in[5];
    const float* tau_n1 = (const float*)d_in[6];
    const float* tau_n2 = (const float*)d_in[7];
    const float* Wr     = (const float*)d_in[8];
    const float* br     = (const float*)d_in[9];
    const float* mem0   = (const float*)d_in[10];
    const float* spike0 = (const float*)d_in[11];
    float* out = (float*)d_out;

    // workspace: 3.1 (Wp) + 154.1 (Xp) + 205.5 (d) + 6.4 (spikes) = 369 MB
    char* p = (char*)d_ws;
    unsigned short* Wp = (unsigned short*)p;  p += (size_t)3 * 1024 * IN * 2;
    unsigned short* Xp = (unsigned short*)p;  p += (size_t)3 * MH * IN * 2;
    float* d1buf = (float*)p;                 p += (size_t)MH * HD * 4;
    float* d2buf = (float*)p;                 p += (size_t)MH * HD * 4;
    unsigned short* spikes = (unsigned short*)p;

    const size_t WPS = (size_t)1024 * IN;    // W plane stride (elems)
    const size_t XPS = (size_t)MH * IN;      // X plane stride (elems)

    // split W1 (plane rows 0..511) and W2 (rows 512..1023)
    split3<<<dim3(128), dim3(256), 0, stream>>>(
        W1, Wp, Wp + WPS, Wp + 2 * WPS, (long)HD * IN / 8);
    split3<<<dim3(128), dim3(256), 0, stream>>>(
        W2, Wp + (size_t)HD * IN, Wp + WPS + (size_t)HD * IN,
        Wp + 2 * WPS + (size_t)HD * IN, (long)HD * IN / 8);

    for (int half = 0; half < 2; ++half) {
        split3<<<dim3((unsigned)(((long)MH * IN / 8 + 255) / 256)), dim3(256), 0, stream>>>(
            X + (size_t)half * MH * IN, Xp, Xp + XPS, Xp + 2 * XPS, (long)MH * IN / 8);
        gemm_bf16x3<<<dim3(392 * 8), dim3(256), 0, stream>>>(
            Xp, Wp, b1, b2, d1buf, d2buf);
        scan_half<<<dim3(512), dim3(64), 0, stream>>>(
            d1buf, d2buf, tau_m, tau_n1, tau_n2, mem0, spike0,
            spikes, half * 64);
    }
    readout<<<dim3(BB * TT / 256), dim3(256), 0, stream>>>(spikes, Wr, br, out);
}